// Round 7
// baseline (221.320 us; speedup 1.0000x reference)
//
#include <hip/hip_runtime.h>
#include <math.h>

typedef float f32x4 __attribute__((ext_vector_type(4)));
typedef _Float16 half8 __attribute__((ext_vector_type(8)));
typedef _Float16 half4 __attribute__((ext_vector_type(4)));

__device__ __forceinline__ void gload16(const void* gsrc, void* ldst) {
  __builtin_amdgcn_global_load_lds(
      (const __attribute__((address_space(1))) void*)gsrc,
      (__attribute__((address_space(3))) void*)ldst, 16, 0, 0);
}

// ---------------------------------------------------------------------------
// f16 MFMA GEMM. A: M x K row-major f16 (lda). B: N x K row-major f16 (ldb).
// BK = 32*KP per barrier phase. LDS keeps 64-B rows via KP planes
// ([NB][KP][rows][32]) so global_load_lds's LINEAR lane->LDS mapping (4
// lanes/row) stays valid per plane. NB=2: double-buffered async prefetch;
// NB=1: single phase (K == BK). XOR bank swizzle on global source col +
// ds_read col. 4 waves 2x2.
// EPI: 0=QKV(q/k f16 (b,h,s,d); v f16 transposed (b,h,d,s); bias by z)
//      1=f16 out, z-linear (scores)
//      2=PV -> ctx16 (b,s,h,d)
//      4=f16 out + bias + gelu
//      5=f32 partial out at z*sOz (split-K)
// ---------------------------------------------------------------------------
template<int NI, int NJ, int KP, int NB, int EPI>
__global__ __launch_bounds__(256)
void gemm16(const _Float16* __restrict__ Ag, const _Float16* __restrict__ Bg,
            const float* __restrict__ bias0, const float* __restrict__ bias1,
            const float* __restrict__ bias2,
            float* __restrict__ outf, _Float16* __restrict__ oh0,
            _Float16* __restrict__ oh1, _Float16* __restrict__ oh2,
            int M, int N, int K, int lda, int ldb, int ldc,
            long sAz, long sBz, long sOz, float alpha)
{
  constexpr int BM = 32 * NI, BN = 32 * NJ, BK = 32 * KP;
  __shared__ __align__(16) _Float16 As[NB][KP][BM][32];
  __shared__ __align__(16) _Float16 Bs[NB][KP][BN][32];

  const int z = blockIdx.z;
  const _Float16* A = Ag + (long)z * sAz;
  const _Float16* B = Bg + (long)z * sBz;

  const int tid = threadIdx.x, lane = tid & 63, wid = tid >> 6;
  const int m0 = blockIdx.x * BM, n0 = blockIdx.y * BN;
  const int l15 = lane & 15;
  const int wm = (wid >> 1) * (16 * NI), wn = (wid & 1) * (16 * NJ);
  const int lr = lane >> 2;                             // 4 lanes per 64-B row
  const int scol = ((lane & 3) ^ (lane >> 4)) * 8;      // pre-swizzled src col
  const int fcol = ((lane >> 4) ^ (l15 >> 2)) * 8;      // swizzled read col

  f32x4 acc[NI][NJ] = {};

  auto stage = [&](int bf, int kk) {
#pragma unroll
    for (int g = wid; g < BM / 16; g += 4)
#pragma unroll
      for (int kp = 0; kp < KP; ++kp)
        gload16(A + (long)(m0 + g * 16 + lr) * lda + kk + kp * 32 + scol,
                &As[bf][kp][g * 16][0]);
#pragma unroll
    for (int g = wid; g < BN / 16; g += 4)
#pragma unroll
      for (int kp = 0; kp < KP; ++kp)
        gload16(B + (long)(n0 + g * 16 + lr) * ldb + kk + kp * 32 + scol,
                &Bs[bf][kp][g * 16][0]);
  };

  stage(0, 0);
  asm volatile("s_waitcnt vmcnt(0)" ::: "memory");
  __syncthreads();

  int buf = 0;
  for (int k0 = 0; k0 < K; k0 += BK) {
    if (NB == 2 && k0 + BK < K) stage(buf ^ 1, k0 + BK);   // async prefetch
#pragma unroll
    for (int kp = 0; kp < KP; ++kp) {
      half8 af[NI], bfr[NJ];
#pragma unroll
      for (int i = 0; i < NI; ++i)
        af[i] = *reinterpret_cast<const half8*>(&As[buf][kp][wm + i * 16 + l15][fcol]);
#pragma unroll
      for (int j = 0; j < NJ; ++j)
        bfr[j] = *reinterpret_cast<const half8*>(&Bs[buf][kp][wn + j * 16 + l15][fcol]);
#pragma unroll
      for (int i = 0; i < NI; ++i)
#pragma unroll
        for (int j = 0; j < NJ; ++j)
          acc[i][j] = __builtin_amdgcn_mfma_f32_16x16x32_f16(af[i], bfr[j], acc[i][j], 0, 0, 0);
    }
    if (k0 + BK < K) {
      asm volatile("s_waitcnt vmcnt(0)" ::: "memory");  // next tile landed
      __syncthreads();
      buf ^= 1;
    }
  }

#pragma unroll
  for (int i = 0; i < NI; ++i) {
#pragma unroll
    for (int j = 0; j < NJ; ++j) {
      const int row0 = m0 + wm + i * 16 + ((lane >> 4) << 2);
      const int col = n0 + wn + j * 16 + l15;
      if constexpr (EPI == 0) {
        const float* bb = (z == 0) ? bias0 : (z == 1) ? bias1 : bias2;
        const float bv = bb[col];
        const int b = row0 >> 9, h = col >> 6, d = col & 63;
        if (z == 2) {
          half4 pk;
#pragma unroll
          for (int r = 0; r < 4; ++r) pk[r] = (_Float16)(acc[i][j][r] + bv);
          *reinterpret_cast<half4*>(
              &oh2[((long)((b * 12 + h) * 64 + d)) * 512 + (row0 & 511)]) = pk;
        } else {
          _Float16* dst = (z == 0) ? oh0 : oh1;
#pragma unroll
          for (int r = 0; r < 4; ++r)
            dst[((long)((b * 12 + h) * 512 + (row0 & 511) + r)) * 64 + d] =
                (_Float16)(acc[i][j][r] + bv);
        }
      } else {
#pragma unroll
        for (int r = 0; r < 4; ++r) {
          const int row = row0 + r;
          float v = acc[i][j][r] * alpha;
          if constexpr (EPI == 1) {
            oh0[(long)z * sOz + (long)row * ldc + col] = (_Float16)v;
          } else if constexpr (EPI == 2) {
            const int zb = z / 12, zh = z - 12 * zb;
            oh0[((long)(zb * 512 + row)) * 768 + zh * 64 + col] = (_Float16)v;
          } else if constexpr (EPI == 4) {
            v += bias0[col];
            v = 0.5f * v * (1.0f + erff(v * 0.70710678118654752440f));
            oh0[(long)row * ldc + col] = (_Float16)v;
          } else if constexpr (EPI == 5) {
            outf[(long)z * sOz + (long)row * ldc + col] = v;
          }
        }
      }
    }
  }
}

// ---------------------------------------------------------------------------
// Fused prep: all weight transposes (f32->f16) + hidden f32->f16, one launch.
// Block ranges: [0,2304) WqT/WkT/WvT/WoT (4 x 576 tiles of 24x24);
// [2304,4608) WiT (96x24); [4608,6912) WfT (24x96); [6912,8448) h16 flat.
// ---------------------------------------------------------------------------
__global__ __launch_bounds__(256)
void prep_kernel(const float* __restrict__ Wq, const float* __restrict__ Wk,
                 const float* __restrict__ Wv, const float* __restrict__ Wo,
                 const float* __restrict__ Wi, const float* __restrict__ Wf,
                 const float* __restrict__ hidden,
                 _Float16* __restrict__ w4t, _Float16* __restrict__ wiT,
                 _Float16* __restrict__ wfT, _Float16* __restrict__ h16)
{
  const int id = blockIdx.x, tid = threadIdx.x;
  if (id >= 6912) {  // flat f32 -> f16 on hidden
    const long i = (long)(id - 6912) * 256 + tid;
    const float4 v = reinterpret_cast<const float4*>(hidden)[i];
    half4 h = {(_Float16)v.x, (_Float16)v.y, (_Float16)v.z, (_Float16)v.w};
    *reinterpret_cast<half4*>(h16 + i * 4) = h;
    return;
  }
  const float* src; _Float16* dst; int R, C, cx, ry;
  if (id < 2304) {
    const int m = id / 576, t = id - m * 576;
    src = (m == 0) ? Wq : (m == 1) ? Wk : (m == 2) ? Wv : Wo;
    dst = w4t + (long)m * 768 * 768;
    R = 768; C = 768; cx = t % 24; ry = t / 24;
  } else if (id < 4608) {
    const int t = id - 2304;
    src = Wi; dst = wiT; R = 768; C = 3072; cx = t % 96; ry = t / 96;
  } else {
    const int t = id - 4608;
    src = Wf; dst = wfT; R = 3072; C = 768; cx = t % 24; ry = t / 24;
  }
  __shared__ float tbuf[32][33];
  const int tx = tid & 31, ty = tid >> 5;
  const int c0 = cx * 32, r0 = ry * 32;
#pragma unroll
  for (int yy = ty; yy < 32; yy += 8)
    tbuf[yy][tx] = src[(long)(r0 + yy) * C + c0 + tx];
  __syncthreads();
#pragma unroll
  for (int yy = ty; yy < 32; yy += 8)
    dst[(long)(c0 + yy) * R + r0 + tx] = (_Float16)tbuf[tx][yy];
}

// ---------------------------------------------------------------------------
// Per (b,i), fused: qr[h,r] = sum_d q[b,h,i,d]*Wr[r,d] (in-block);
// s[h][j] = scores16 + (qr.br)/8 + mask; s += (qr . rel)/8 via MFMA with rel
// B-fragments straight from global (streamed once, no barriers in the loop);
// softmax over j; probs f16 in-place. Wr/qrow staging overlays s[].
// ---------------------------------------------------------------------------
__global__ __launch_bounds__(256)
void relsm3(const float* __restrict__ rel, const float* __restrict__ graph,
            const _Float16* __restrict__ q16, const float* __restrict__ Wr,
            const float* __restrict__ br,
            _Float16* __restrict__ sc)   // in: scores f16, out: probs f16
{
  __shared__ float s[12][512];           // phase 0/1 overlay: wr[64][65]+qrow
  __shared__ float qrl[12][64];
  __shared__ float gl[512];
  __shared__ float qb8[12];

  float* wrbuf = &s[0][0];               // [64][65] = 4160 floats
  float* qrowbuf = wrbuf + 64 * 65;      // [12][64] = 768 floats (<= 6144 tot)

  const int bi = blockIdx.x;
  const int b = bi >> 9, i = bi & 511;
  const int tid = threadIdx.x, lane = tid & 63, wid = tid >> 6;
  const int l15 = lane & 15, lk = (lane >> 4) * 8;

  // P0: stage Wr, q-row, graph
  for (int t = tid; t < 4096; t += 256) wrbuf[(t >> 6) * 65 + (t & 63)] = Wr[t];
  for (int t = tid; t < 768; t += 256) {
    const int h = t >> 6, d = t & 63;
    qrowbuf[h * 64 + d] = (float)q16[((long)((b * 12 + h) * 512 + i)) * 64 + d];
  }
  for (int t = tid; t < 512; t += 256) gl[t] = graph[(long)bi * 512 + t];
  __syncthreads();

  // P1: qr + qbr
  for (int o = tid; o < 768; o += 256) {
    const int h = o >> 6, r = o & 63;
    float ssum = 0.f;
#pragma unroll 8
    for (int d = 0; d < 64; ++d) ssum += qrowbuf[h * 64 + d] * wrbuf[r * 65 + d];
    qrl[h][r] = ssum;
  }
  if (tid < 12) {
    float ssum = 0.f;
#pragma unroll 8
    for (int d = 0; d < 64; ++d) ssum += qrowbuf[tid * 64 + d] * br[d];
    qb8[tid] = ssum * 0.125f;
  }
  __syncthreads();

  // P2: qa fragments + s init (overwrites wr/qrow overlay)
  half8 qa0 = {}, qa1 = {};
  if (l15 < 12) {
#pragma unroll
    for (int e = 0; e < 8; ++e) {
      qa0[e] = (_Float16)qrl[l15][lk + e];
      qa1[e] = (_Float16)qrl[l15][32 + lk + e];
    }
  }
  for (int t = tid; t < 6144; t += 256) {
    const int h = t >> 9, j = t & 511;
    s[h][j] = (float)sc[(((long)(b * 12 + h) * 512) + i) * 512 + j]
            + qb8[h] + (1.0f - gl[j]) * (-1.0e9f);
  }
  __syncthreads();

  // P3: stream rel once, MFMA rel-dot, RMW s (no barriers inside)
  const long rbase = ((long)bi * 512 + wid * 16 + l15) * 64 + lk;
  const int jj0 = wid * 16 + l15;
  for (int jt = 0; jt < 512; jt += 64) {
    const float* rp = rel + rbase + (long)jt * 64;
    const float4 v0 = *reinterpret_cast<const float4*>(rp);
    const float4 v1 = *reinterpret_cast<const float4*>(rp + 4);
    const float4 v2 = *reinterpret_cast<const float4*>(rp + 32);
    const float4 v3 = *reinterpret_cast<const float4*>(rp + 36);
    half8 b0, b1;
    b0[0] = (_Float16)v0.x; b0[1] = (_Float16)v0.y; b0[2] = (_Float16)v0.z; b0[3] = (_Float16)v0.w;
    b0[4] = (_Float16)v1.x; b0[5] = (_Float16)v1.y; b0[6] = (_Float16)v1.z; b0[7] = (_Float16)v1.w;
    b1[0] = (_Float16)v2.x; b1[1] = (_Float16)v2.y; b1[2] = (_Float16)v2.z; b1[3] = (_Float16)v2.w;
    b1[4] = (_Float16)v3.x; b1[5] = (_Float16)v3.y; b1[6] = (_Float16)v3.z; b1[7] = (_Float16)v3.w;
    f32x4 acc = {};
    acc = __builtin_amdgcn_mfma_f32_16x16x32_f16(qa0, b0, acc, 0, 0, 0);
    acc = __builtin_amdgcn_mfma_f32_16x16x32_f16(qa1, b1, acc, 0, 0, 0);
#pragma unroll
    for (int r = 0; r < 4; ++r) {
      const int h = ((lane >> 4) << 2) + r;
      if (h < 12) s[h][jt + jj0] += acc[r] * 0.125f;
    }
  }
  __syncthreads();

  // P4: softmax + write probs f16
  for (int h = wid; h < 12; h += 4) {
    float vals[8];
    float mx = -3.4e38f;
#pragma unroll
    for (int t = 0; t < 8; ++t) {
      vals[t] = s[h][lane + (t << 6)];
      mx = fmaxf(mx, vals[t]);
    }
#pragma unroll
    for (int off = 32; off > 0; off >>= 1) mx = fmaxf(mx, __shfl_xor(mx, off, 64));
    float sum = 0.f;
#pragma unroll
    for (int t = 0; t < 8; ++t) { vals[t] = __expf(vals[t] - mx); sum += vals[t]; }
#pragma unroll
    for (int off = 32; off > 0; off >>= 1) sum += __shfl_xor(sum, off, 64);
    const float inv = 1.0f / sum;
    const long base = (((long)(b * 12 + h) * 512) + i) * 512;
#pragma unroll
    for (int t = 0; t < 8; ++t) sc[base + lane + (t << 6)] = (_Float16)(vals[t] * inv);
  }
}

// ---------------------------------------------------------------------------
// x = p0 + p1 + bias + res (f32, fixed order), then row LayerNorm over 768.
// Optional f16 secondary output.
// ---------------------------------------------------------------------------
__global__ __launch_bounds__(256)
void ln2_kernel(const float* __restrict__ p0, const float* __restrict__ p1,
                const float* __restrict__ bias, const float* __restrict__ res,
                const float* __restrict__ g, const float* __restrict__ bta,
                float* __restrict__ out, _Float16* __restrict__ out16)
{
  __shared__ float red[8];
  const long row = blockIdx.x;
  const int tid = threadIdx.x;
  const long o0i = row * 768 + tid, o1i = o0i + 256, o2i = o0i + 512;
  const float v0 = p0[o0i] + p1[o0i] + bias[tid] + res[o0i];
  const float v1 = p0[o1i] + p1[o1i] + bias[tid + 256] + res[o1i];
  const float v2 = p0[o2i] + p1[o2i] + bias[tid + 512] + res[o2i];
  float sum = v0 + v1 + v2;
#pragma unroll
  for (int off = 32; off > 0; off >>= 1) sum += __shfl_xor(sum, off, 64);
  const int wv = tid >> 6, ln = tid & 63;
  if (ln == 0) red[wv] = sum;
  __syncthreads();
  const float mean = (red[0] + red[1] + red[2] + red[3]) * (1.0f / 768.0f);
  const float d0 = v0 - mean, d1 = v1 - mean, d2 = v2 - mean;
  float sq = d0 * d0 + d1 * d1 + d2 * d2;
#pragma unroll
  for (int off = 32; off > 0; off >>= 1) sq += __shfl_xor(sq, off, 64);
  if (ln == 0) red[4 + wv] = sq;
  __syncthreads();
  const float var = (red[4] + red[5] + red[6] + red[7]) * (1.0f / 768.0f);
  const float rstd = rsqrtf(var + 1e-12f);
  const float o0 = g[tid] * d0 * rstd + bta[tid];
  const float o1 = g[tid + 256] * d1 * rstd + bta[tid + 256];
  const float o2 = g[tid + 512] * d2 * rstd + bta[tid + 512];
  float* orow = out + row * 768;
  orow[tid] = o0; orow[tid + 256] = o1; orow[tid + 512] = o2;
  if (out16) {
    _Float16* hrow = out16 + row * 768;
    hrow[tid] = (_Float16)o0; hrow[tid + 256] = (_Float16)o1; hrow[tid + 512] = (_Float16)o2;
  }
}

// ---------------------------------------------------------------------------
extern "C" void kernel_launch(void* const* d_in, const int* in_sizes, int n_in,
                              void* d_out, int out_size, void* d_ws, size_t ws_size,
                              hipStream_t stream)
{
  const float* hidden = (const float*)d_in[0];
  const float* graph  = (const float*)d_in[1];
  const float* rel    = (const float*)d_in[2];
  const float* Wq = (const float*)d_in[3];  const float* bq = (const float*)d_in[4];
  const float* Wk = (const float*)d_in[5];  const float* bk = (const float*)d_in[6];
  const float* Wv = (const float*)d_in[7];  const float* bv = (const float*)d_in[8];
  const float* Wr = (const float*)d_in[9];  const float* br = (const float*)d_in[10];
  const float* Wo = (const float*)d_in[11]; const float* bo = (const float*)d_in[12];
  const float* g1 = (const float*)d_in[13]; const float* b1 = (const float*)d_in[14];
  const float* Wi = (const float*)d_in[15]; const float* bi = (const float*)d_in[16];
  const float* Wf = (const float*)d_in[17]; const float* bff = (const float*)d_in[18];
  const float* g2 = (const float*)d_in[19]; const float* b2 = (const float*)d_in[20];
  float* out = (float*)d_out;

  // ---- workspace carving (bytes, 256B-aligned blocks)
  char* base = (char*)d_ws;
  size_t off = 0;
  auto carve = [&](size_t bytes) { void* p = base + off; off += (bytes + 255) & ~255UL; return p; };
  _Float16* h16   = (_Float16*)carve(2048L * 768 * 2);
  _Float16* w4t   = (_Float16*)carve(4L * 768 * 768 * 2);   // WqT,WkT,WvT,WoT
  _Float16* wiT   = (_Float16*)carve(3072L * 768 * 2);
  _Float16* wfT   = (_Float16*)carve(768L * 3072 * 2);
  _Float16* q16   = (_Float16*)carve(2048L * 768 * 2);      // (b,h,s,d)
  _Float16* k16   = (_Float16*)carve(2048L * 768 * 2);      // (b,h,s,d)
  _Float16* v16t  = (_Float16*)carve(2048L * 768 * 2);      // (b,h,d,s)
  _Float16* sc16  = (_Float16*)carve(48L * 512 * 512 * 2);  // scores -> probs
  _Float16* ctx16 = (_Float16*)carve(2048L * 768 * 2);      // (b,s,h,d)
  float*    pk01  = (float*)carve(2L * 2048 * 768 * 4);     // split-K partials
  float*    attn  = (float*)carve(2048L * 768 * 4);
  _Float16* attn16= (_Float16*)carve(2048L * 768 * 2);
  _Float16* inter16=(_Float16*)carve(2048L * 3072 * 2);

  const dim3 blk(256);
  const long W44 = 768L * 768;
  const long PSTR = 2048L * 768;

  // ---- fused operand conversion (one launch)
  hipLaunchKernelGGL(prep_kernel, dim3(8448), blk, 0, stream,
    Wq, Wk, Wv, Wo, Wi, Wf, hidden, w4t, wiT, wfT, h16);

  // ---- QKV fused (z=0,1,2): 64x96 tiles, BK=64, grid 768 (3/CU balanced)
  hipLaunchKernelGGL((gemm16<2, 3, 2, 2, 0>), dim3(32, 8, 3), blk, 0, stream,
    h16, w4t, bq, bk, bv,
    (float*)nullptr, q16, k16, v16t,
    2048, 768, 768, 768, 768, 768, 0L, W44, 0L, 1.0f);

  // ---- scores = (q @ k^T)/8 f16: 128x128, K=64 single-phase, grid 768
  hipLaunchKernelGGL((gemm16<4, 4, 2, 1, 1>), dim3(4, 4, 48), blk, 0, stream,
    q16, k16, (const float*)nullptr, (const float*)nullptr, (const float*)nullptr,
    (float*)nullptr, sc16, (_Float16*)nullptr, (_Float16*)nullptr,
    512, 512, 64, 64, 64, 512, 32768L, 32768L, 262144L, 0.125f);

  // ---- qr (in-block) + rel term + mask + softmax (in-place f16)
  hipLaunchKernelGGL(relsm3, dim3(2048), blk, 0, stream,
    rel, graph, q16, Wr, br, sc16);

  // ---- ctx = probs @ v : 32x64 tiles, BK=64, grid 768
  hipLaunchKernelGGL((gemm16<1, 2, 2, 2, 2>), dim3(16, 1, 48), blk, 0, stream,
    sc16, v16t, (const float*)nullptr, (const float*)nullptr, (const float*)nullptr,
    (float*)nullptr, ctx16, (_Float16*)nullptr, (_Float16*)nullptr,
    512, 64, 512, 512, 512, 768, 262144L, 32768L, 0L, 1.0f);

  // ---- ctx @ Wo split-K (z=2 halves of 768), 64x96, grid 512 (2/CU balanced)
  hipLaunchKernelGGL((gemm16<2, 3, 2, 2, 5>), dim3(32, 8, 2), blk, 0, stream,
    ctx16, w4t + 3 * W44, (const float*)nullptr, (const float*)nullptr, (const float*)nullptr,
    pk01, (_Float16*)nullptr, (_Float16*)nullptr, (_Float16*)nullptr,
    2048, 768, 384, 768, 768, 768, 384L, 384L, PSTR, 1.0f);
  hipLaunchKernelGGL(ln2_kernel, dim3(2048), blk, 0, stream,
    pk01, pk01 + PSTR, bo, hidden, g1, b1, attn, attn16);

  // ---- inter = gelu(attn @ Wi + bi) : 128x96, BK=64, grid 512 (2/CU balanced)
  hipLaunchKernelGGL((gemm16<4, 3, 2, 2, 4>), dim3(16, 32, 1), blk, 0, stream,
    attn16, wiT, bi, (const float*)nullptr, (const float*)nullptr,
    (float*)nullptr, inter16, (_Float16*)nullptr, (_Float16*)nullptr,
    2048, 3072, 768, 768, 768, 3072, 0L, 0L, 0L, 1.0f);

  // ---- inter @ Wf split-K (z=2 halves of 3072), 64x96, grid 512 (2/CU)
  hipLaunchKernelGGL((gemm16<2, 3, 2, 2, 5>), dim3(32, 8, 2), blk, 0, stream,
    inter16, wfT, (const float*)nullptr, (const float*)nullptr, (const float*)nullptr,
    pk01, (_Float16*)nullptr, (_Float16*)nullptr, (_Float16*)nullptr,
    2048, 768, 1536, 3072, 3072, 768, 1536L, 1536L, PSTR, 1.0f);
  hipLaunchKernelGGL(ln2_kernel, dim3(2048), blk, 0, stream,
    pk01, pk01 + PSTR, bff, attn, g2, b2, out, (_Float16*)nullptr);
}

// Round 8
// 209.872 us; speedup vs baseline: 1.0545x; 1.0545x over previous
//
#include <hip/hip_runtime.h>
#include <math.h>

typedef float f32x4 __attribute__((ext_vector_type(4)));
typedef _Float16 half8 __attribute__((ext_vector_type(8)));
typedef _Float16 half4 __attribute__((ext_vector_type(4)));

__device__ __forceinline__ void gload16(const void* gsrc, void* ldst) {
  __builtin_amdgcn_global_load_lds(
      (const __attribute__((address_space(1))) void*)gsrc,
      (__attribute__((address_space(3))) void*)ldst, 16, 0, 0);
}

// ---------------------------------------------------------------------------
// f16 MFMA GEMM. A: M x K row-major f16 (lda). B: N x K row-major f16 (ldb).
// BK = 32*KP per barrier phase. LDS keeps 64-B rows via KP planes
// ([NB][KP][rows][32]) so global_load_lds's LINEAR lane->LDS mapping (4
// lanes/row) stays valid per plane. NB=2: double-buffered async prefetch;
// NB=1: single phase (K == BK). XOR bank swizzle on global source col +
// ds_read col. 4 waves 2x2.
// EPI: 0=QKV(q/k f16 (b,h,s,d); v f16 transposed (b,h,d,s); bias by z)
//      1=f16 out, z-linear (scores)
//      2=PV -> ctx16 (b,s,h,d)
//      4=f16 out + bias + gelu
//      5=f32 partial out at z*sOz (split-K)
// ---------------------------------------------------------------------------
template<int NI, int NJ, int KP, int NB, int EPI>
__global__ __launch_bounds__(256)
void gemm16(const _Float16* __restrict__ Ag, const _Float16* __restrict__ Bg,
            const float* __restrict__ bias0, const float* __restrict__ bias1,
            const float* __restrict__ bias2,
            float* __restrict__ outf, _Float16* __restrict__ oh0,
            _Float16* __restrict__ oh1, _Float16* __restrict__ oh2,
            int M, int N, int K, int lda, int ldb, int ldc,
            long sAz, long sBz, long sOz, float alpha)
{
  constexpr int BM = 32 * NI, BN = 32 * NJ, BK = 32 * KP;
  __shared__ __align__(16) _Float16 As[NB][KP][BM][32];
  __shared__ __align__(16) _Float16 Bs[NB][KP][BN][32];

  const int z = blockIdx.z;
  const _Float16* A = Ag + (long)z * sAz;
  const _Float16* B = Bg + (long)z * sBz;

  const int tid = threadIdx.x, lane = tid & 63, wid = tid >> 6;
  const int m0 = blockIdx.x * BM, n0 = blockIdx.y * BN;
  const int l15 = lane & 15;
  const int wm = (wid >> 1) * (16 * NI), wn = (wid & 1) * (16 * NJ);
  const int lr = lane >> 2;                             // 4 lanes per 64-B row
  const int scol = ((lane & 3) ^ (lane >> 4)) * 8;      // pre-swizzled src col
  const int fcol = ((lane >> 4) ^ (l15 >> 2)) * 8;      // swizzled read col

  f32x4 acc[NI][NJ] = {};

  auto stage = [&](int bf, int kk) {
#pragma unroll
    for (int g = wid; g < BM / 16; g += 4)
#pragma unroll
      for (int kp = 0; kp < KP; ++kp)
        gload16(A + (long)(m0 + g * 16 + lr) * lda + kk + kp * 32 + scol,
                &As[bf][kp][g * 16][0]);
#pragma unroll
    for (int g = wid; g < BN / 16; g += 4)
#pragma unroll
      for (int kp = 0; kp < KP; ++kp)
        gload16(B + (long)(n0 + g * 16 + lr) * ldb + kk + kp * 32 + scol,
                &Bs[bf][kp][g * 16][0]);
  };

  stage(0, 0);
  asm volatile("s_waitcnt vmcnt(0)" ::: "memory");
  __syncthreads();

  int buf = 0;
  for (int k0 = 0; k0 < K; k0 += BK) {
    if (NB == 2 && k0 + BK < K) stage(buf ^ 1, k0 + BK);   // async prefetch
#pragma unroll
    for (int kp = 0; kp < KP; ++kp) {
      half8 af[NI], bfr[NJ];
#pragma unroll
      for (int i = 0; i < NI; ++i)
        af[i] = *reinterpret_cast<const half8*>(&As[buf][kp][wm + i * 16 + l15][fcol]);
#pragma unroll
      for (int j = 0; j < NJ; ++j)
        bfr[j] = *reinterpret_cast<const half8*>(&Bs[buf][kp][wn + j * 16 + l15][fcol]);
#pragma unroll
      for (int i = 0; i < NI; ++i)
#pragma unroll
        for (int j = 0; j < NJ; ++j)
          acc[i][j] = __builtin_amdgcn_mfma_f32_16x16x32_f16(af[i], bfr[j], acc[i][j], 0, 0, 0);
    }
    if (k0 + BK < K) {
      asm volatile("s_waitcnt vmcnt(0)" ::: "memory");  // next tile landed
      __syncthreads();
      buf ^= 1;
    }
  }

#pragma unroll
  for (int i = 0; i < NI; ++i) {
#pragma unroll
    for (int j = 0; j < NJ; ++j) {
      const int row0 = m0 + wm + i * 16 + ((lane >> 4) << 2);
      const int col = n0 + wn + j * 16 + l15;
      if constexpr (EPI == 0) {
        const float* bb = (z == 0) ? bias0 : (z == 1) ? bias1 : bias2;
        const float bv = bb[col];
        const int b = row0 >> 9, h = col >> 6, d = col & 63;
        if (z == 2) {
          half4 pk;
#pragma unroll
          for (int r = 0; r < 4; ++r) pk[r] = (_Float16)(acc[i][j][r] + bv);
          *reinterpret_cast<half4*>(
              &oh2[((long)((b * 12 + h) * 64 + d)) * 512 + (row0 & 511)]) = pk;
        } else {
          _Float16* dst = (z == 0) ? oh0 : oh1;
#pragma unroll
          for (int r = 0; r < 4; ++r)
            dst[((long)((b * 12 + h) * 512 + (row0 & 511) + r)) * 64 + d] =
                (_Float16)(acc[i][j][r] + bv);
        }
      } else {
#pragma unroll
        for (int r = 0; r < 4; ++r) {
          const int row = row0 + r;
          float v = acc[i][j][r] * alpha;
          if constexpr (EPI == 1) {
            oh0[(long)z * sOz + (long)row * ldc + col] = (_Float16)v;
          } else if constexpr (EPI == 2) {
            const int zb = z / 12, zh = z - 12 * zb;
            oh0[((long)(zb * 512 + row)) * 768 + zh * 64 + col] = (_Float16)v;
          } else if constexpr (EPI == 4) {
            v += bias0[col];
            v = 0.5f * v * (1.0f + erff(v * 0.70710678118654752440f));
            oh0[(long)row * ldc + col] = (_Float16)v;
          } else if constexpr (EPI == 5) {
            outf[(long)z * sOz + (long)row * ldc + col] = v;
          }
        }
      }
    }
  }
}

// ---------------------------------------------------------------------------
// Fused prep: all weight transposes (f32->f16) + hidden f32->f16, one launch.
// Vectorized: float4 loads into LDS, half4 stores out.
// Block ranges: [0,2304) WqT/WkT/WvT/WoT (4 x 576 tiles of 24x24);
// [2304,4608) WiT (96x24); [4608,6912) WfT (24x96); [6912,8448) h16 flat.
// ---------------------------------------------------------------------------
__global__ __launch_bounds__(256)
void prep_kernel(const float* __restrict__ Wq, const float* __restrict__ Wk,
                 const float* __restrict__ Wv, const float* __restrict__ Wo,
                 const float* __restrict__ Wi, const float* __restrict__ Wf,
                 const float* __restrict__ hidden,
                 _Float16* __restrict__ w4t, _Float16* __restrict__ wiT,
                 _Float16* __restrict__ wfT, _Float16* __restrict__ h16)
{
  const int id = blockIdx.x, tid = threadIdx.x;
  if (id >= 6912) {  // flat f32 -> f16 on hidden
    const long i = (long)(id - 6912) * 256 + tid;
    const float4 v = reinterpret_cast<const float4*>(hidden)[i];
    half4 h = {(_Float16)v.x, (_Float16)v.y, (_Float16)v.z, (_Float16)v.w};
    *reinterpret_cast<half4*>(h16 + i * 4) = h;
    return;
  }
  const float* src; _Float16* dst; int R, C, cx, ry;
  if (id < 2304) {
    const int m = id / 576, t = id - m * 576;
    src = (m == 0) ? Wq : (m == 1) ? Wk : (m == 2) ? Wv : Wo;
    dst = w4t + (long)m * 768 * 768;
    R = 768; C = 768; cx = t % 24; ry = t / 24;
  } else if (id < 4608) {
    const int t = id - 2304;
    src = Wi; dst = wiT; R = 768; C = 3072; cx = t % 96; ry = t / 96;
  } else {
    const int t = id - 4608;
    src = Wf; dst = wfT; R = 3072; C = 768; cx = t % 24; ry = t / 24;
  }
  __shared__ float tbuf[32][33];
  const int c0 = cx * 32, r0 = ry * 32;
  {
    // load 32x32 f32 tile: 256 threads = 32 rows x 8 float4 lanes
    const int yy = tid >> 3, x4 = (tid & 7) << 2;
    const float4 v = *reinterpret_cast<const float4*>(
        src + (long)(r0 + yy) * C + c0 + x4);
    tbuf[yy][x4] = v.x; tbuf[yy][x4 + 1] = v.y;
    tbuf[yy][x4 + 2] = v.z; tbuf[yy][x4 + 3] = v.w;
  }
  __syncthreads();
  {
    // store 32x32 f16 transposed: 256 threads = 32 c-rows x 8 half4 lanes
    const int yy = tid >> 3, x4 = (tid & 7) << 2;
    half4 h;
#pragma unroll
    for (int e = 0; e < 4; ++e) h[e] = (_Float16)tbuf[x4 + e][yy];
    *reinterpret_cast<half4*>(dst + (long)(c0 + yy) * R + r0 + x4) = h;
  }
}

// ---------------------------------------------------------------------------
// Per (b,i), fused: qr[h,r] = sum_d q[b,h,i,d]*Wr[r,d] (in-block);
// s[h][j] = scores16 + (qr.br)/8 + mask; s += (qr . rel)/8 via MFMA with rel
// B-fragments straight from global (streamed once, no barriers in the loop);
// softmax over j; probs f16 in-place. Wr/qrow staging overlays s[].
// ---------------------------------------------------------------------------
__global__ __launch_bounds__(256)
void relsm3(const float* __restrict__ rel, const float* __restrict__ graph,
            const _Float16* __restrict__ q16, const float* __restrict__ Wr,
            const float* __restrict__ br,
            _Float16* __restrict__ sc)   // in: scores f16, out: probs f16
{
  __shared__ float s[12][512];           // phase 0/1 overlay: wr[64][65]+qrow
  __shared__ float qrl[12][64];
  __shared__ float gl[512];
  __shared__ float qb8[12];

  float* wrbuf = &s[0][0];               // [64][65] = 4160 floats
  float* qrowbuf = wrbuf + 64 * 65;      // [12][64] = 768 floats (<= 6144 tot)

  const int bi = blockIdx.x;
  const int b = bi >> 9, i = bi & 511;
  const int tid = threadIdx.x, lane = tid & 63, wid = tid >> 6;
  const int l15 = lane & 15, lk = (lane >> 4) * 8;

  // P0: stage Wr, q-row, graph
  for (int t = tid; t < 4096; t += 256) wrbuf[(t >> 6) * 65 + (t & 63)] = Wr[t];
  for (int t = tid; t < 768; t += 256) {
    const int h = t >> 6, d = t & 63;
    qrowbuf[h * 64 + d] = (float)q16[((long)((b * 12 + h) * 512 + i)) * 64 + d];
  }
  for (int t = tid; t < 512; t += 256) gl[t] = graph[(long)bi * 512 + t];
  __syncthreads();

  // P1: qr + qbr
  for (int o = tid; o < 768; o += 256) {
    const int h = o >> 6, r = o & 63;
    float ssum = 0.f;
#pragma unroll 8
    for (int d = 0; d < 64; ++d) ssum += qrowbuf[h * 64 + d] * wrbuf[r * 65 + d];
    qrl[h][r] = ssum;
  }
  if (tid < 12) {
    float ssum = 0.f;
#pragma unroll 8
    for (int d = 0; d < 64; ++d) ssum += qrowbuf[tid * 64 + d] * br[d];
    qb8[tid] = ssum * 0.125f;
  }
  __syncthreads();

  // P2: qa fragments + s init (overwrites wr/qrow overlay); vectorized half8
  half8 qa0 = {}, qa1 = {};
  if (l15 < 12) {
#pragma unroll
    for (int e = 0; e < 8; ++e) {
      qa0[e] = (_Float16)qrl[l15][lk + e];
      qa1[e] = (_Float16)qrl[l15][32 + lk + e];
    }
  }
#pragma unroll
  for (int t = 0; t < 3; ++t) {
    const int idx = t * 256 + tid;       // 768 half8-groups = 6144 elems
    const int h = idx >> 6, j8 = (idx & 63) << 3;
    const half8 v = *reinterpret_cast<const half8*>(
        &sc[(((long)(b * 12 + h) * 512) + i) * 512 + j8]);
    const float add = qb8[h];
#pragma unroll
    for (int e = 0; e < 8; ++e)
      s[h][j8 + e] = (float)v[e] + add + (1.0f - gl[j8 + e]) * (-1.0e9f);
  }
  __syncthreads();

  // P3: stream rel once, MFMA rel-dot, RMW s (no barriers inside)
  const long rbase = ((long)bi * 512 + wid * 16 + l15) * 64 + lk;
  const int jj0 = wid * 16 + l15;
  for (int jt = 0; jt < 512; jt += 64) {
    const float* rp = rel + rbase + (long)jt * 64;
    const float4 v0 = *reinterpret_cast<const float4*>(rp);
    const float4 v1 = *reinterpret_cast<const float4*>(rp + 4);
    const float4 v2 = *reinterpret_cast<const float4*>(rp + 32);
    const float4 v3 = *reinterpret_cast<const float4*>(rp + 36);
    half8 b0, b1;
    b0[0] = (_Float16)v0.x; b0[1] = (_Float16)v0.y; b0[2] = (_Float16)v0.z; b0[3] = (_Float16)v0.w;
    b0[4] = (_Float16)v1.x; b0[5] = (_Float16)v1.y; b0[6] = (_Float16)v1.z; b0[7] = (_Float16)v1.w;
    b1[0] = (_Float16)v2.x; b1[1] = (_Float16)v2.y; b1[2] = (_Float16)v2.z; b1[3] = (_Float16)v2.w;
    b1[4] = (_Float16)v3.x; b1[5] = (_Float16)v3.y; b1[6] = (_Float16)v3.z; b1[7] = (_Float16)v3.w;
    f32x4 acc = {};
    acc = __builtin_amdgcn_mfma_f32_16x16x32_f16(qa0, b0, acc, 0, 0, 0);
    acc = __builtin_amdgcn_mfma_f32_16x16x32_f16(qa1, b1, acc, 0, 0, 0);
#pragma unroll
    for (int r = 0; r < 4; ++r) {
      const int h = ((lane >> 4) << 2) + r;
      if (h < 12) s[h][jt + jj0] += acc[r] * 0.125f;
    }
  }
  __syncthreads();

  // P4: softmax + write probs f16
  for (int h = wid; h < 12; h += 4) {
    float vals[8];
    float mx = -3.4e38f;
#pragma unroll
    for (int t = 0; t < 8; ++t) {
      vals[t] = s[h][lane + (t << 6)];
      mx = fmaxf(mx, vals[t]);
    }
#pragma unroll
    for (int off = 32; off > 0; off >>= 1) mx = fmaxf(mx, __shfl_xor(mx, off, 64));
    float sum = 0.f;
#pragma unroll
    for (int t = 0; t < 8; ++t) { vals[t] = __expf(vals[t] - mx); sum += vals[t]; }
#pragma unroll
    for (int off = 32; off > 0; off >>= 1) sum += __shfl_xor(sum, off, 64);
    const float inv = 1.0f / sum;
    const long base = (((long)(b * 12 + h) * 512) + i) * 512;
#pragma unroll
    for (int t = 0; t < 8; ++t) sc[base + lane + (t << 6)] = (_Float16)(vals[t] * inv);
  }
}

// ---------------------------------------------------------------------------
// x = p0 + p1 + bias + res (f32, fixed order), then row LayerNorm over 768.
// Optional f16 secondary output.
// ---------------------------------------------------------------------------
__global__ __launch_bounds__(256)
void ln2_kernel(const float* __restrict__ p0, const float* __restrict__ p1,
                const float* __restrict__ bias, const float* __restrict__ res,
                const float* __restrict__ g, const float* __restrict__ bta,
                float* __restrict__ out, _Float16* __restrict__ out16)
{
  __shared__ float red[8];
  const long row = blockIdx.x;
  const int tid = threadIdx.x;
  const long o0i = row * 768 + tid, o1i = o0i + 256, o2i = o0i + 512;
  const float v0 = p0[o0i] + p1[o0i] + bias[tid] + res[o0i];
  const float v1 = p0[o1i] + p1[o1i] + bias[tid + 256] + res[o1i];
  const float v2 = p0[o2i] + p1[o2i] + bias[tid + 512] + res[o2i];
  float sum = v0 + v1 + v2;
#pragma unroll
  for (int off = 32; off > 0; off >>= 1) sum += __shfl_xor(sum, off, 64);
  const int wv = tid >> 6, ln = tid & 63;
  if (ln == 0) red[wv] = sum;
  __syncthreads();
  const float mean = (red[0] + red[1] + red[2] + red[3]) * (1.0f / 768.0f);
  const float d0 = v0 - mean, d1 = v1 - mean, d2 = v2 - mean;
  float sq = d0 * d0 + d1 * d1 + d2 * d2;
#pragma unroll
  for (int off = 32; off > 0; off >>= 1) sq += __shfl_xor(sq, off, 64);
  if (ln == 0) red[4 + wv] = sq;
  __syncthreads();
  const float var = (red[4] + red[5] + red[6] + red[7]) * (1.0f / 768.0f);
  const float rstd = rsqrtf(var + 1e-12f);
  const float o0 = g[tid] * d0 * rstd + bta[tid];
  const float o1 = g[tid + 256] * d1 * rstd + bta[tid + 256];
  const float o2 = g[tid + 512] * d2 * rstd + bta[tid + 512];
  float* orow = out + row * 768;
  orow[tid] = o0; orow[tid + 256] = o1; orow[tid + 512] = o2;
  if (out16) {
    _Float16* hrow = out16 + row * 768;
    hrow[tid] = (_Float16)o0; hrow[tid + 256] = (_Float16)o1; hrow[tid + 512] = (_Float16)o2;
  }
}

// ---------------------------------------------------------------------------
extern "C" void kernel_launch(void* const* d_in, const int* in_sizes, int n_in,
                              void* d_out, int out_size, void* d_ws, size_t ws_size,
                              hipStream_t stream)
{
  const float* hidden = (const float*)d_in[0];
  const float* graph  = (const float*)d_in[1];
  const float* rel    = (const float*)d_in[2];
  const float* Wq = (const float*)d_in[3];  const float* bq = (const float*)d_in[4];
  const float* Wk = (const float*)d_in[5];  const float* bk = (const float*)d_in[6];
  const float* Wv = (const float*)d_in[7];  const float* bv = (const float*)d_in[8];
  const float* Wr = (const float*)d_in[9];  const float* br = (const float*)d_in[10];
  const float* Wo = (const float*)d_in[11]; const float* bo = (const float*)d_in[12];
  const float* g1 = (const float*)d_in[13]; const float* b1 = (const float*)d_in[14];
  const float* Wi = (const float*)d_in[15]; const float* bi = (const float*)d_in[16];
  const float* Wf = (const float*)d_in[17]; const float* bff = (const float*)d_in[18];
  const float* g2 = (const float*)d_in[19]; const float* b2 = (const float*)d_in[20];
  float* out = (float*)d_out;

  // ---- workspace carving (bytes, 256B-aligned blocks)
  char* base = (char*)d_ws;
  size_t off = 0;
  auto carve = [&](size_t bytes) { void* p = base + off; off += (bytes + 255) & ~255UL; return p; };
  _Float16* h16   = (_Float16*)carve(2048L * 768 * 2);
  _Float16* w4t   = (_Float16*)carve(4L * 768 * 768 * 2);   // WqT,WkT,WvT,WoT
  _Float16* wiT   = (_Float16*)carve(3072L * 768 * 2);
  _Float16* wfT   = (_Float16*)carve(768L * 3072 * 2);
  _Float16* q16   = (_Float16*)carve(2048L * 768 * 2);      // (b,h,s,d)
  _Float16* k16   = (_Float16*)carve(2048L * 768 * 2);      // (b,h,s,d)
  _Float16* v16t  = (_Float16*)carve(2048L * 768 * 2);      // (b,h,d,s)
  _Float16* sc16  = (_Float16*)carve(48L * 512 * 512 * 2);  // scores -> probs
  _Float16* ctx16 = (_Float16*)carve(2048L * 768 * 2);      // (b,s,h,d)
  float*    pk01  = (float*)carve(2L * 2048 * 768 * 4);     // split-K partials
  float*    attn  = (float*)carve(2048L * 768 * 4);
  _Float16* attn16= (_Float16*)carve(2048L * 768 * 2);
  _Float16* inter16=(_Float16*)carve(2048L * 3072 * 2);

  const dim3 blk(256);
  const long W44 = 768L * 768;
  const long PSTR = 2048L * 768;

  // ---- fused operand conversion (one launch)
  hipLaunchKernelGGL(prep_kernel, dim3(8448), blk, 0, stream,
    Wq, Wk, Wv, Wo, Wi, Wf, hidden, w4t, wiT, wfT, h16);

  // ---- QKV fused (z=0,1,2): 64x96 tiles, BK=64, grid 768
  hipLaunchKernelGGL((gemm16<2, 3, 2, 2, 0>), dim3(32, 8, 3), blk, 0, stream,
    h16, w4t, bq, bk, bv,
    (float*)nullptr, q16, k16, v16t,
    2048, 768, 768, 768, 768, 768, 0L, W44, 0L, 1.0f);

  // ---- scores = (q @ k^T)/8 f16: 128x128, K=64 single-phase, grid 768
  hipLaunchKernelGGL((gemm16<4, 4, 2, 1, 1>), dim3(4, 4, 48), blk, 0, stream,
    q16, k16, (const float*)nullptr, (const float*)nullptr, (const float*)nullptr,
    (float*)nullptr, sc16, (_Float16*)nullptr, (_Float16*)nullptr,
    512, 512, 64, 64, 64, 512, 32768L, 32768L, 262144L, 0.125f);

  // ---- qr (in-block) + rel term + mask + softmax (in-place f16)
  hipLaunchKernelGGL(relsm3, dim3(2048), blk, 0, stream,
    rel, graph, q16, Wr, br, sc16);

  // ---- ctx = probs @ v : 32x64 tiles, BK=128 (4 phases), grid 768, 3/CU
  hipLaunchKernelGGL((gemm16<1, 2, 4, 2, 2>), dim3(16, 1, 48), blk, 0, stream,
    sc16, v16t, (const float*)nullptr, (const float*)nullptr, (const float*)nullptr,
    (float*)nullptr, ctx16, (_Float16*)nullptr, (_Float16*)nullptr,
    512, 64, 512, 512, 512, 768, 262144L, 32768L, 0L, 1.0f);

  // ---- ctx @ Wo split-K (z=2 halves of 768), 64x96, grid 512
  hipLaunchKernelGGL((gemm16<2, 3, 2, 2, 5>), dim3(32, 8, 2), blk, 0, stream,
    ctx16, w4t + 3 * W44, (const float*)nullptr, (const float*)nullptr, (const float*)nullptr,
    pk01, (_Float16*)nullptr, (_Float16*)nullptr, (_Float16*)nullptr,
    2048, 768, 384, 768, 768, 768, 384L, 384L, PSTR, 1.0f);
  hipLaunchKernelGGL(ln2_kernel, dim3(2048), blk, 0, stream,
    pk01, pk01 + PSTR, bo, hidden, g1, b1, attn, attn16);

  // ---- inter = gelu(attn @ Wi + bi) : 128x96, BK=64, grid 512
  hipLaunchKernelGGL((gemm16<4, 3, 2, 2, 4>), dim3(16, 32, 1), blk, 0, stream,
    attn16, wiT, bi, (const float*)nullptr, (const float*)nullptr,
    (float*)nullptr, inter16, (_Float16*)nullptr, (_Float16*)nullptr,
    2048, 3072, 768, 768, 768, 3072, 0L, 0L, 0L, 1.0f);

  // ---- inter @ Wf split-K (z=2 halves of 3072), 64x96, grid 512
  hipLaunchKernelGGL((gemm16<2, 3, 2, 2, 5>), dim3(32, 8, 2), blk, 0, stream,
    inter16, wfT, (const float*)nullptr, (const float*)nullptr, (const float*)nullptr,
    pk01, (_Float16*)nullptr, (_Float16*)nullptr, (_Float16*)nullptr,
    2048, 768, 1536, 3072, 3072, 768, 1536L, 1536L, PSTR, 1.0f);
  hipLaunchKernelGGL(ln2_kernel, dim3(2048), blk, 0, stream,
    pk01, pk01 + PSTR, bff, attn, g2, b2, out, (_Float16*)nullptr);
}

// Round 9
// 201.386 us; speedup vs baseline: 1.0990x; 1.0421x over previous
//
#include <hip/hip_runtime.h>
#include <math.h>

typedef float f32x4 __attribute__((ext_vector_type(4)));
typedef _Float16 half8 __attribute__((ext_vector_type(8)));
typedef _Float16 half4 __attribute__((ext_vector_type(4)));
typedef _Float16 half2v __attribute__((ext_vector_type(2)));

__device__ __forceinline__ void gload16(const void* gsrc, void* ldst) {
  __builtin_amdgcn_global_load_lds(
      (const __attribute__((address_space(1))) void*)gsrc,
      (__attribute__((address_space(3))) void*)ldst, 16, 0, 0);
}

// ---------------------------------------------------------------------------
// f16 MFMA GEMM. A: M x K row-major f16 (lda). B: N x K row-major f16 (ldb).
// BK = 32*KP per barrier phase. LDS keeps 64-B rows via KP planes
// ([NB][KP][rows][32]) so global_load_lds's LINEAR lane->LDS mapping (4
// lanes/row) stays valid per plane. NB=2: double-buffered async prefetch;
// NB=1: single phase (K == BK). XOR bank swizzle on global source col +
// ds_read col. 4 waves 2x2.
// EPI: 0=QKV(q/k f16 (b,h,s,d); v f16 transposed (b,h,d,s); bias by z)
//      1=f16 out, z-linear (scores)
//      2=PV -> ctx16 (b,s,h,d)
//      4=f16 out + bias + gelu
//      5=f32 partial out at z*sOz (split-K)
// ---------------------------------------------------------------------------
template<int NI, int NJ, int KP, int NB, int EPI>
__global__ __launch_bounds__(256)
void gemm16(const _Float16* __restrict__ Ag, const _Float16* __restrict__ Bg,
            const float* __restrict__ bias0, const float* __restrict__ bias1,
            const float* __restrict__ bias2,
            float* __restrict__ outf, _Float16* __restrict__ oh0,
            _Float16* __restrict__ oh1, _Float16* __restrict__ oh2,
            int M, int N, int K, int lda, int ldb, int ldc,
            long sAz, long sBz, long sOz, float alpha)
{
  constexpr int BM = 32 * NI, BN = 32 * NJ, BK = 32 * KP;
  __shared__ __align__(16) _Float16 As[NB][KP][BM][32];
  __shared__ __align__(16) _Float16 Bs[NB][KP][BN][32];

  const int z = blockIdx.z;
  const _Float16* A = Ag + (long)z * sAz;
  const _Float16* B = Bg + (long)z * sBz;

  const int tid = threadIdx.x, lane = tid & 63, wid = tid >> 6;
  const int m0 = blockIdx.x * BM, n0 = blockIdx.y * BN;
  const int l15 = lane & 15;
  const int wm = (wid >> 1) * (16 * NI), wn = (wid & 1) * (16 * NJ);
  const int lr = lane >> 2;                             // 4 lanes per 64-B row
  const int scol = ((lane & 3) ^ (lane >> 4)) * 8;      // pre-swizzled src col
  const int fcol = ((lane >> 4) ^ (l15 >> 2)) * 8;      // swizzled read col

  f32x4 acc[NI][NJ] = {};

  auto stage = [&](int bf, int kk) {
#pragma unroll
    for (int g = wid; g < BM / 16; g += 4)
#pragma unroll
      for (int kp = 0; kp < KP; ++kp)
        gload16(A + (long)(m0 + g * 16 + lr) * lda + kk + kp * 32 + scol,
                &As[bf][kp][g * 16][0]);
#pragma unroll
    for (int g = wid; g < BN / 16; g += 4)
#pragma unroll
      for (int kp = 0; kp < KP; ++kp)
        gload16(B + (long)(n0 + g * 16 + lr) * ldb + kk + kp * 32 + scol,
                &Bs[bf][kp][g * 16][0]);
  };

  stage(0, 0);
  asm volatile("s_waitcnt vmcnt(0)" ::: "memory");
  __syncthreads();

  int buf = 0;
  for (int k0 = 0; k0 < K; k0 += BK) {
    if (NB == 2 && k0 + BK < K) stage(buf ^ 1, k0 + BK);   // async prefetch
#pragma unroll
    for (int kp = 0; kp < KP; ++kp) {
      half8 af[NI], bfr[NJ];
#pragma unroll
      for (int i = 0; i < NI; ++i)
        af[i] = *reinterpret_cast<const half8*>(&As[buf][kp][wm + i * 16 + l15][fcol]);
#pragma unroll
      for (int j = 0; j < NJ; ++j)
        bfr[j] = *reinterpret_cast<const half8*>(&Bs[buf][kp][wn + j * 16 + l15][fcol]);
#pragma unroll
      for (int i = 0; i < NI; ++i)
#pragma unroll
        for (int j = 0; j < NJ; ++j)
          acc[i][j] = __builtin_amdgcn_mfma_f32_16x16x32_f16(af[i], bfr[j], acc[i][j], 0, 0, 0);
    }
    if (k0 + BK < K) {
      asm volatile("s_waitcnt vmcnt(0)" ::: "memory");  // next tile landed
      __syncthreads();
      buf ^= 1;
    }
  }

#pragma unroll
  for (int i = 0; i < NI; ++i) {
#pragma unroll
    for (int j = 0; j < NJ; ++j) {
      const int row0 = m0 + wm + i * 16 + ((lane >> 4) << 2);
      const int col = n0 + wn + j * 16 + l15;
      if constexpr (EPI == 0) {
        const float* bb = (z == 0) ? bias0 : (z == 1) ? bias1 : bias2;
        const float bv = bb[col];
        const int b = row0 >> 9, h = col >> 6, d = col & 63;
        if (z == 2) {
          half4 pk;
#pragma unroll
          for (int r = 0; r < 4; ++r) pk[r] = (_Float16)(acc[i][j][r] + bv);
          *reinterpret_cast<half4*>(
              &oh2[((long)((b * 12 + h) * 64 + d)) * 512 + (row0 & 511)]) = pk;
        } else {
          _Float16* dst = (z == 0) ? oh0 : oh1;
#pragma unroll
          for (int r = 0; r < 4; ++r)
            dst[((long)((b * 12 + h) * 512 + (row0 & 511) + r)) * 64 + d] =
                (_Float16)(acc[i][j][r] + bv);
        }
      } else {
#pragma unroll
        for (int r = 0; r < 4; ++r) {
          const int row = row0 + r;
          float v = acc[i][j][r] * alpha;
          if constexpr (EPI == 1) {
            oh0[(long)z * sOz + (long)row * ldc + col] = (_Float16)v;
          } else if constexpr (EPI == 2) {
            const int zb = z / 12, zh = z - 12 * zb;
            oh0[((long)(zb * 512 + row)) * 768 + zh * 64 + col] = (_Float16)v;
          } else if constexpr (EPI == 4) {
            v += bias0[col];
            v = 0.5f * v * (1.0f + erff(v * 0.70710678118654752440f));
            oh0[(long)row * ldc + col] = (_Float16)v;
          } else if constexpr (EPI == 5) {
            outf[(long)z * sOz + (long)row * ldc + col] = v;
          }
        }
      }
    }
  }
}

// ---------------------------------------------------------------------------
// Fused prep: all weight transposes (f32->f16) + hidden f32->f16, one launch.
// Vectorized: float4 loads into LDS, half4 stores out.
// ---------------------------------------------------------------------------
__global__ __launch_bounds__(256)
void prep_kernel(const float* __restrict__ Wq, const float* __restrict__ Wk,
                 const float* __restrict__ Wv, const float* __restrict__ Wo,
                 const float* __restrict__ Wi, const float* __restrict__ Wf,
                 const float* __restrict__ hidden,
                 _Float16* __restrict__ w4t, _Float16* __restrict__ wiT,
                 _Float16* __restrict__ wfT, _Float16* __restrict__ h16)
{
  const int id = blockIdx.x, tid = threadIdx.x;
  if (id >= 6912) {  // flat f32 -> f16 on hidden
    const long i = (long)(id - 6912) * 256 + tid;
    const float4 v = reinterpret_cast<const float4*>(hidden)[i];
    half4 h = {(_Float16)v.x, (_Float16)v.y, (_Float16)v.z, (_Float16)v.w};
    *reinterpret_cast<half4*>(h16 + i * 4) = h;
    return;
  }
  const float* src; _Float16* dst; int R, C, cx, ry;
  if (id < 2304) {
    const int m = id / 576, t = id - m * 576;
    src = (m == 0) ? Wq : (m == 1) ? Wk : (m == 2) ? Wv : Wo;
    dst = w4t + (long)m * 768 * 768;
    R = 768; C = 768; cx = t % 24; ry = t / 24;
  } else if (id < 4608) {
    const int t = id - 2304;
    src = Wi; dst = wiT; R = 768; C = 3072; cx = t % 96; ry = t / 96;
  } else {
    const int t = id - 4608;
    src = Wf; dst = wfT; R = 3072; C = 768; cx = t % 24; ry = t / 24;
  }
  __shared__ float tbuf[32][33];
  const int c0 = cx * 32, r0 = ry * 32;
  {
    const int yy = tid >> 3, x4 = (tid & 7) << 2;
    const float4 v = *reinterpret_cast<const float4*>(
        src + (long)(r0 + yy) * C + c0 + x4);
    tbuf[yy][x4] = v.x; tbuf[yy][x4 + 1] = v.y;
    tbuf[yy][x4 + 2] = v.z; tbuf[yy][x4 + 3] = v.w;
  }
  __syncthreads();
  {
    const int yy = tid >> 3, x4 = (tid & 7) << 2;
    half4 h;
#pragma unroll
    for (int e = 0; e < 4; ++e) h[e] = (_Float16)tbuf[x4 + e][yy];
    *reinterpret_cast<half4*>(dst + (long)(c0 + yy) * R + r0 + x4) = h;
  }
}

// ---------------------------------------------------------------------------
// Per (b,i), fused: qr (in-block) + scores + rel-dot + mask + softmax.
// ---------------------------------------------------------------------------
__global__ __launch_bounds__(256)
void relsm3(const float* __restrict__ rel, const float* __restrict__ graph,
            const _Float16* __restrict__ q16, const float* __restrict__ Wr,
            const float* __restrict__ br,
            _Float16* __restrict__ sc)   // in: scores f16, out: probs f16
{
  __shared__ float s[12][512];           // phase 0/1 overlay: wr[64][65]+qrow
  __shared__ float qrl[12][64];
  __shared__ float gl[512];
  __shared__ float qb8[12];

  float* wrbuf = &s[0][0];               // [64][65] = 4160 floats
  float* qrowbuf = wrbuf + 64 * 65;      // [12][64] = 768 floats (<= 6144 tot)

  const int bi = blockIdx.x;
  const int b = bi >> 9, i = bi & 511;
  const int tid = threadIdx.x, lane = tid & 63, wid = tid >> 6;
  const int l15 = lane & 15, lk = (lane >> 4) * 8;

  // P0: stage Wr, q-row, graph
  for (int t = tid; t < 4096; t += 256) wrbuf[(t >> 6) * 65 + (t & 63)] = Wr[t];
  for (int t = tid; t < 768; t += 256) {
    const int h = t >> 6, d = t & 63;
    qrowbuf[h * 64 + d] = (float)q16[((long)((b * 12 + h) * 512 + i)) * 64 + d];
  }
  for (int t = tid; t < 512; t += 256) gl[t] = graph[(long)bi * 512 + t];
  __syncthreads();

  // P1: qr + qbr
  for (int o = tid; o < 768; o += 256) {
    const int h = o >> 6, r = o & 63;
    float ssum = 0.f;
#pragma unroll 8
    for (int d = 0; d < 64; ++d) ssum += qrowbuf[h * 64 + d] * wrbuf[r * 65 + d];
    qrl[h][r] = ssum;
  }
  if (tid < 12) {
    float ssum = 0.f;
#pragma unroll 8
    for (int d = 0; d < 64; ++d) ssum += qrowbuf[tid * 64 + d] * br[d];
    qb8[tid] = ssum * 0.125f;
  }
  __syncthreads();

  // P2: qa fragments + s init (overwrites wr/qrow overlay); vectorized half8
  half8 qa0 = {}, qa1 = {};
  if (l15 < 12) {
#pragma unroll
    for (int e = 0; e < 8; ++e) {
      qa0[e] = (_Float16)qrl[l15][lk + e];
      qa1[e] = (_Float16)qrl[l15][32 + lk + e];
    }
  }
#pragma unroll
  for (int t = 0; t < 3; ++t) {
    const int idx = t * 256 + tid;       // 768 half8-groups = 6144 elems
    const int h = idx >> 6, j8 = (idx & 63) << 3;
    const half8 v = *reinterpret_cast<const half8*>(
        &sc[(((long)(b * 12 + h) * 512) + i) * 512 + j8]);
    const float add = qb8[h];
#pragma unroll
    for (int e = 0; e < 8; ++e)
      s[h][j8 + e] = (float)v[e] + add + (1.0f - gl[j8 + e]) * (-1.0e9f);
  }
  __syncthreads();

  // P3: stream rel once, MFMA rel-dot, RMW s (no barriers inside)
  const long rbase = ((long)bi * 512 + wid * 16 + l15) * 64 + lk;
  const int jj0 = wid * 16 + l15;
  for (int jt = 0; jt < 512; jt += 64) {
    const float* rp = rel + rbase + (long)jt * 64;
    const float4 v0 = *reinterpret_cast<const float4*>(rp);
    const float4 v1 = *reinterpret_cast<const float4*>(rp + 4);
    const float4 v2 = *reinterpret_cast<const float4*>(rp + 32);
    const float4 v3 = *reinterpret_cast<const float4*>(rp + 36);
    half8 b0, b1;
    b0[0] = (_Float16)v0.x; b0[1] = (_Float16)v0.y; b0[2] = (_Float16)v0.z; b0[3] = (_Float16)v0.w;
    b0[4] = (_Float16)v1.x; b0[5] = (_Float16)v1.y; b0[6] = (_Float16)v1.z; b0[7] = (_Float16)v1.w;
    b1[0] = (_Float16)v2.x; b1[1] = (_Float16)v2.y; b1[2] = (_Float16)v2.z; b1[3] = (_Float16)v2.w;
    b1[4] = (_Float16)v3.x; b1[5] = (_Float16)v3.y; b1[6] = (_Float16)v3.z; b1[7] = (_Float16)v3.w;
    f32x4 acc = {};
    acc = __builtin_amdgcn_mfma_f32_16x16x32_f16(qa0, b0, acc, 0, 0, 0);
    acc = __builtin_amdgcn_mfma_f32_16x16x32_f16(qa1, b1, acc, 0, 0, 0);
#pragma unroll
    for (int r = 0; r < 4; ++r) {
      const int h = ((lane >> 4) << 2) + r;
      if (h < 12) s[h][jt + jj0] += acc[r] * 0.125f;
    }
  }
  __syncthreads();

  // P4: softmax + write probs as half2 (4B/lane stores)
  for (int h = wid; h < 12; h += 4) {
    float v0[4], v1[4];
    float mx = -3.4e38f;
#pragma unroll
    for (int t = 0; t < 4; ++t) {
      const int j0 = (t << 7) + (lane << 1);
      v0[t] = s[h][j0]; v1[t] = s[h][j0 + 1];
      mx = fmaxf(mx, fmaxf(v0[t], v1[t]));
    }
#pragma unroll
    for (int off = 32; off > 0; off >>= 1) mx = fmaxf(mx, __shfl_xor(mx, off, 64));
    float sum = 0.f;
#pragma unroll
    for (int t = 0; t < 4; ++t) {
      v0[t] = __expf(v0[t] - mx); v1[t] = __expf(v1[t] - mx);
      sum += v0[t] + v1[t];
    }
#pragma unroll
    for (int off = 32; off > 0; off >>= 1) sum += __shfl_xor(sum, off, 64);
    const float inv = 1.0f / sum;
    const long base = (((long)(b * 12 + h) * 512) + i) * 512;
#pragma unroll
    for (int t = 0; t < 4; ++t) {
      const int j0 = (t << 7) + (lane << 1);
      half2v pk = {(_Float16)(v0[t] * inv), (_Float16)(v1[t] * inv)};
      *reinterpret_cast<half2v*>(&sc[base + j0]) = pk;
    }
  }
}

// ---------------------------------------------------------------------------
// x = p0 + p1 + bias + res (f32, fixed order), then row LayerNorm over 768.
// Optional f16 secondary output.
// ---------------------------------------------------------------------------
__global__ __launch_bounds__(256)
void ln2_kernel(const float* __restrict__ p0, const float* __restrict__ p1,
                const float* __restrict__ bias, const float* __restrict__ res,
                const float* __restrict__ g, const float* __restrict__ bta,
                float* __restrict__ out, _Float16* __restrict__ out16)
{
  __shared__ float red[8];
  const long row = blockIdx.x;
  const int tid = threadIdx.x;
  const long o0i = row * 768 + tid, o1i = o0i + 256, o2i = o0i + 512;
  const float v0 = p0[o0i] + p1[o0i] + bias[tid] + res[o0i];
  const float v1 = p0[o1i] + p1[o1i] + bias[tid + 256] + res[o1i];
  const float v2 = p0[o2i] + p1[o2i] + bias[tid + 512] + res[o2i];
  float sum = v0 + v1 + v2;
#pragma unroll
  for (int off = 32; off > 0; off >>= 1) sum += __shfl_xor(sum, off, 64);
  const int wv = tid >> 6, ln = tid & 63;
  if (ln == 0) red[wv] = sum;
  __syncthreads();
  const float mean = (red[0] + red[1] + red[2] + red[3]) * (1.0f / 768.0f);
  const float d0 = v0 - mean, d1 = v1 - mean, d2 = v2 - mean;
  float sq = d0 * d0 + d1 * d1 + d2 * d2;
#pragma unroll
  for (int off = 32; off > 0; off >>= 1) sq += __shfl_xor(sq, off, 64);
  if (ln == 0) red[4 + wv] = sq;
  __syncthreads();
  const float var = (red[4] + red[5] + red[6] + red[7]) * (1.0f / 768.0f);
  const float rstd = rsqrtf(var + 1e-12f);
  const float o0 = g[tid] * d0 * rstd + bta[tid];
  const float o1 = g[tid + 256] * d1 * rstd + bta[tid + 256];
  const float o2 = g[tid + 512] * d2 * rstd + bta[tid + 512];
  float* orow = out + row * 768;
  orow[tid] = o0; orow[tid + 256] = o1; orow[tid + 512] = o2;
  if (out16) {
    _Float16* hrow = out16 + row * 768;
    hrow[tid] = (_Float16)o0; hrow[tid + 256] = (_Float16)o1; hrow[tid + 512] = (_Float16)o2;
  }
}

// ---------------------------------------------------------------------------
extern "C" void kernel_launch(void* const* d_in, const int* in_sizes, int n_in,
                              void* d_out, int out_size, void* d_ws, size_t ws_size,
                              hipStream_t stream)
{
  const float* hidden = (const float*)d_in[0];
  const float* graph  = (const float*)d_in[1];
  const float* rel    = (const float*)d_in[2];
  const float* Wq = (const float*)d_in[3];  const float* bq = (const float*)d_in[4];
  const float* Wk = (const float*)d_in[5];  const float* bk = (const float*)d_in[6];
  const float* Wv = (const float*)d_in[7];  const float* bv = (const float*)d_in[8];
  const float* Wr = (const float*)d_in[9];  const float* br = (const float*)d_in[10];
  const float* Wo = (const float*)d_in[11]; const float* bo = (const float*)d_in[12];
  const float* g1 = (const float*)d_in[13]; const float* b1 = (const float*)d_in[14];
  const float* Wi = (const float*)d_in[15]; const float* bi = (const float*)d_in[16];
  const float* Wf = (const float*)d_in[17]; const float* bff = (const float*)d_in[18];
  const float* g2 = (const float*)d_in[19]; const float* b2 = (const float*)d_in[20];
  float* out = (float*)d_out;

  // ---- workspace carving (bytes, 256B-aligned blocks)
  char* base = (char*)d_ws;
  size_t off = 0;
  auto carve = [&](size_t bytes) { void* p = base + off; off += (bytes + 255) & ~255UL; return p; };
  _Float16* h16   = (_Float16*)carve(2048L * 768 * 2);
  _Float16* w4t   = (_Float16*)carve(4L * 768 * 768 * 2);   // WqT,WkT,WvT,WoT
  _Float16* wiT   = (_Float16*)carve(3072L * 768 * 2);
  _Float16* wfT   = (_Float16*)carve(768L * 3072 * 2);
  _Float16* q16   = (_Float16*)carve(2048L * 768 * 2);      // (b,h,s,d)
  _Float16* k16   = (_Float16*)carve(2048L * 768 * 2);      // (b,h,s,d)
  _Float16* v16t  = (_Float16*)carve(2048L * 768 * 2);      // (b,h,d,s)
  _Float16* sc16  = (_Float16*)carve(48L * 512 * 512 * 2);  // scores -> probs
  _Float16* ctx16 = (_Float16*)carve(2048L * 768 * 2);      // (b,s,h,d)
  float*    pk01  = (float*)carve(2L * 2048 * 768 * 4);     // split-K partials
  float*    attn  = (float*)carve(2048L * 768 * 4);
  _Float16* attn16= (_Float16*)carve(2048L * 768 * 2);
  _Float16* inter16=(_Float16*)carve(2048L * 3072 * 2);

  const dim3 blk(256);
  const long W44 = 768L * 768;
  const long PSTR = 2048L * 768;

  // ---- fused operand conversion (one launch)
  hipLaunchKernelGGL(prep_kernel, dim3(8448), blk, 0, stream,
    Wq, Wk, Wv, Wo, Wi, Wf, hidden, w4t, wiT, wfT, h16);

  // ---- QKV fused (z=0,1,2): 64x96 tiles, BK=64, grid 768
  hipLaunchKernelGGL((gemm16<2, 3, 2, 2, 0>), dim3(32, 8, 3), blk, 0, stream,
    h16, w4t, bq, bk, bv,
    (float*)nullptr, q16, k16, v16t,
    2048, 768, 768, 768, 768, 768, 0L, W44, 0L, 1.0f);

  // ---- scores = (q @ k^T)/8 f16: 128x128, K=64 single-phase, grid 768
  hipLaunchKernelGGL((gemm16<4, 4, 2, 1, 1>), dim3(4, 4, 48), blk, 0, stream,
    q16, k16, (const float*)nullptr, (const float*)nullptr, (const float*)nullptr,
    (float*)nullptr, sc16, (_Float16*)nullptr, (_Float16*)nullptr,
    512, 512, 64, 64, 64, 512, 32768L, 32768L, 262144L, 0.125f);

  // ---- qr (in-block) + rel term + mask + softmax (in-place f16)
  hipLaunchKernelGGL(relsm3, dim3(2048), blk, 0, stream,
    rel, graph, q16, Wr, br, sc16);

  // ---- ctx = probs @ v : 32x64 tiles, BK=128 (4 phases), grid 768, 3/CU
  hipLaunchKernelGGL((gemm16<1, 2, 4, 2, 2>), dim3(16, 1, 48), blk, 0, stream,
    sc16, v16t, (const float*)nullptr, (const float*)nullptr, (const float*)nullptr,
    (float*)nullptr, ctx16, (_Float16*)nullptr, (_Float16*)nullptr,
    512, 64, 512, 512, 512, 768, 262144L, 32768L, 0L, 1.0f);

  // ---- ctx @ Wo split-K (z=2 halves of 768), 64x96, BK=128 (3 phases), grid 512
  hipLaunchKernelGGL((gemm16<2, 3, 4, 2, 5>), dim3(32, 8, 2), blk, 0, stream,
    ctx16, w4t + 3 * W44, (const float*)nullptr, (const float*)nullptr, (const float*)nullptr,
    pk01, (_Float16*)nullptr, (_Float16*)nullptr, (_Float16*)nullptr,
    2048, 768, 384, 768, 768, 768, 384L, 384L, PSTR, 1.0f);
  hipLaunchKernelGGL(ln2_kernel, dim3(2048), blk, 0, stream,
    pk01, pk01 + PSTR, bo, hidden, g1, b1, attn, attn16);

  // ---- inter = gelu(attn @ Wi + bi) : 128x96, BK=64, grid 512
  hipLaunchKernelGGL((gemm16<4, 3, 2, 2, 4>), dim3(16, 32, 1), blk, 0, stream,
    attn16, wiT, bi, (const float*)nullptr, (const float*)nullptr,
    (float*)nullptr, inter16, (_Float16*)nullptr, (_Float16*)nullptr,
    2048, 3072, 768, 768, 768, 3072, 0L, 0L, 0L, 1.0f);

  // ---- inter @ Wf split-K (z=2 halves of 3072), 64x96, BK=128 (12 phases), grid 512
  hipLaunchKernelGGL((gemm16<2, 3, 4, 2, 5>), dim3(32, 8, 2), blk, 0, stream,
    inter16, wfT, (const float*)nullptr, (const float*)nullptr, (const float*)nullptr,
    pk01, (_Float16*)nullptr, (_Float16*)nullptr, (_Float16*)nullptr,
    2048, 768, 1536, 3072, 3072, 768, 1536L, 1536L, PSTR, 1.0f);
  hipLaunchKernelGGL(ln2_kernel, dim3(2048), blk, 0, stream,
    pk01, pk01 + PSTR, bff, attn, g2, b2, out, (_Float16*)nullptr);
}

// Round 10
// 199.531 us; speedup vs baseline: 1.1092x; 1.0093x over previous
//
#include <hip/hip_runtime.h>
#include <math.h>

typedef float f32x4 __attribute__((ext_vector_type(4)));
typedef _Float16 half8 __attribute__((ext_vector_type(8)));
typedef _Float16 half4 __attribute__((ext_vector_type(4)));
typedef _Float16 half2v __attribute__((ext_vector_type(2)));

__device__ __forceinline__ void gload16(const void* gsrc, void* ldst) {
  __builtin_amdgcn_global_load_lds(
      (const __attribute__((address_space(1))) void*)gsrc,
      (__attribute__((address_space(3))) void*)ldst, 16, 0, 0);
}

// ---------------------------------------------------------------------------
// f16 MFMA GEMM. A: M x K row-major f16 (lda). B: N x K row-major f16 (ldb).
// BK = 32*KP per barrier phase. LDS keeps 64-B rows via KP planes
// ([NB][KP][rows][32]) so global_load_lds's LINEAR lane->LDS mapping (4
// lanes/row) stays valid per plane. NB=2: double-buffered async prefetch;
// NB=1: single phase (K == BK). XOR bank swizzle on global source col +
// ds_read col. 4 waves 2x2.
// EPI: 0=QKV(q/k f16 (b,h,s,d); v f16 transposed (b,h,d,s); bias by z)
//      1=f16 out, z-linear (scores)
//      2=PV -> ctx16 (b,s,h,d)
//      4=f16 out + bias + gelu
//      6=f16 partial out at z*sOz (split-K)
// ---------------------------------------------------------------------------
template<int NI, int NJ, int KP, int NB, int EPI>
__global__ __launch_bounds__(256)
void gemm16(const _Float16* __restrict__ Ag, const _Float16* __restrict__ Bg,
            const float* __restrict__ bias0, const float* __restrict__ bias1,
            const float* __restrict__ bias2,
            float* __restrict__ outf, _Float16* __restrict__ oh0,
            _Float16* __restrict__ oh1, _Float16* __restrict__ oh2,
            int M, int N, int K, int lda, int ldb, int ldc,
            long sAz, long sBz, long sOz, float alpha)
{
  constexpr int BM = 32 * NI, BN = 32 * NJ, BK = 32 * KP;
  __shared__ __align__(16) _Float16 As[NB][KP][BM][32];
  __shared__ __align__(16) _Float16 Bs[NB][KP][BN][32];

  const int z = blockIdx.z;
  const _Float16* A = Ag + (long)z * sAz;
  const _Float16* B = Bg + (long)z * sBz;

  const int tid = threadIdx.x, lane = tid & 63, wid = tid >> 6;
  const int m0 = blockIdx.x * BM, n0 = blockIdx.y * BN;
  const int l15 = lane & 15;
  const int wm = (wid >> 1) * (16 * NI), wn = (wid & 1) * (16 * NJ);
  const int lr = lane >> 2;                             // 4 lanes per 64-B row
  const int scol = ((lane & 3) ^ (lane >> 4)) * 8;      // pre-swizzled src col
  const int fcol = ((lane >> 4) ^ (l15 >> 2)) * 8;      // swizzled read col

  f32x4 acc[NI][NJ] = {};

  auto stage = [&](int bf, int kk) {
#pragma unroll
    for (int g = wid; g < BM / 16; g += 4)
#pragma unroll
      for (int kp = 0; kp < KP; ++kp)
        gload16(A + (long)(m0 + g * 16 + lr) * lda + kk + kp * 32 + scol,
                &As[bf][kp][g * 16][0]);
#pragma unroll
    for (int g = wid; g < BN / 16; g += 4)
#pragma unroll
      for (int kp = 0; kp < KP; ++kp)
        gload16(B + (long)(n0 + g * 16 + lr) * ldb + kk + kp * 32 + scol,
                &Bs[bf][kp][g * 16][0]);
  };

  stage(0, 0);
  asm volatile("s_waitcnt vmcnt(0)" ::: "memory");
  __syncthreads();

  int buf = 0;
  for (int k0 = 0; k0 < K; k0 += BK) {
    if (NB == 2 && k0 + BK < K) stage(buf ^ 1, k0 + BK);   // async prefetch
#pragma unroll
    for (int kp = 0; kp < KP; ++kp) {
      half8 af[NI], bfr[NJ];
#pragma unroll
      for (int i = 0; i < NI; ++i)
        af[i] = *reinterpret_cast<const half8*>(&As[buf][kp][wm + i * 16 + l15][fcol]);
#pragma unroll
      for (int j = 0; j < NJ; ++j)
        bfr[j] = *reinterpret_cast<const half8*>(&Bs[buf][kp][wn + j * 16 + l15][fcol]);
#pragma unroll
      for (int i = 0; i < NI; ++i)
#pragma unroll
        for (int j = 0; j < NJ; ++j)
          acc[i][j] = __builtin_amdgcn_mfma_f32_16x16x32_f16(af[i], bfr[j], acc[i][j], 0, 0, 0);
    }
    if (k0 + BK < K) {
      asm volatile("s_waitcnt vmcnt(0)" ::: "memory");  // next tile landed
      __syncthreads();
      buf ^= 1;
    }
  }

#pragma unroll
  for (int i = 0; i < NI; ++i) {
#pragma unroll
    for (int j = 0; j < NJ; ++j) {
      const int row0 = m0 + wm + i * 16 + ((lane >> 4) << 2);
      const int col = n0 + wn + j * 16 + l15;
      if constexpr (EPI == 0) {
        const float* bb = (z == 0) ? bias0 : (z == 1) ? bias1 : bias2;
        const float bv = bb[col];
        const int b = row0 >> 9, h = col >> 6, d = col & 63;
        if (z == 2) {
          half4 pk;
#pragma unroll
          for (int r = 0; r < 4; ++r) pk[r] = (_Float16)(acc[i][j][r] + bv);
          *reinterpret_cast<half4*>(
              &oh2[((long)((b * 12 + h) * 64 + d)) * 512 + (row0 & 511)]) = pk;
        } else {
          _Float16* dst = (z == 0) ? oh0 : oh1;
#pragma unroll
          for (int r = 0; r < 4; ++r)
            dst[((long)((b * 12 + h) * 512 + (row0 & 511) + r)) * 64 + d] =
                (_Float16)(acc[i][j][r] + bv);
        }
      } else {
#pragma unroll
        for (int r = 0; r < 4; ++r) {
          const int row = row0 + r;
          float v = acc[i][j][r] * alpha;
          if constexpr (EPI == 1) {
            oh0[(long)z * sOz + (long)row * ldc + col] = (_Float16)v;
          } else if constexpr (EPI == 2) {
            const int zb = z / 12, zh = z - 12 * zb;
            oh0[((long)(zb * 512 + row)) * 768 + zh * 64 + col] = (_Float16)v;
          } else if constexpr (EPI == 4) {
            v += bias0[col];
            v = 0.5f * v * (1.0f + erff(v * 0.70710678118654752440f));
            oh0[(long)row * ldc + col] = (_Float16)v;
          } else if constexpr (EPI == 6) {
            oh0[(long)z * sOz + (long)row * ldc + col] = (_Float16)v;
          }
        }
      }
    }
  }
}

// ---------------------------------------------------------------------------
// Fused prep: all weight transposes (f32->f16) + hidden f32->f16, one launch.
// Vectorized: float4 loads into LDS, half4 stores out.
// ---------------------------------------------------------------------------
__global__ __launch_bounds__(256)
void prep_kernel(const float* __restrict__ Wq, const float* __restrict__ Wk,
                 const float* __restrict__ Wv, const float* __restrict__ Wo,
                 const float* __restrict__ Wi, const float* __restrict__ Wf,
                 const float* __restrict__ hidden,
                 _Float16* __restrict__ w4t, _Float16* __restrict__ wiT,
                 _Float16* __restrict__ wfT, _Float16* __restrict__ h16)
{
  const int id = blockIdx.x, tid = threadIdx.x;
  if (id >= 6912) {  // flat f32 -> f16 on hidden
    const long i = (long)(id - 6912) * 256 + tid;
    const float4 v = reinterpret_cast<const float4*>(hidden)[i];
    half4 h = {(_Float16)v.x, (_Float16)v.y, (_Float16)v.z, (_Float16)v.w};
    *reinterpret_cast<half4*>(h16 + i * 4) = h;
    return;
  }
  const float* src; _Float16* dst; int R, C, cx, ry;
  if (id < 2304) {
    const int m = id / 576, t = id - m * 576;
    src = (m == 0) ? Wq : (m == 1) ? Wk : (m == 2) ? Wv : Wo;
    dst = w4t + (long)m * 768 * 768;
    R = 768; C = 768; cx = t % 24; ry = t / 24;
  } else if (id < 4608) {
    const int t = id - 2304;
    src = Wi; dst = wiT; R = 768; C = 3072; cx = t % 96; ry = t / 96;
  } else {
    const int t = id - 4608;
    src = Wf; dst = wfT; R = 3072; C = 768; cx = t % 24; ry = t / 24;
  }
  __shared__ float tbuf[32][33];
  const int c0 = cx * 32, r0 = ry * 32;
  {
    const int yy = tid >> 3, x4 = (tid & 7) << 2;
    const float4 v = *reinterpret_cast<const float4*>(
        src + (long)(r0 + yy) * C + c0 + x4);
    tbuf[yy][x4] = v.x; tbuf[yy][x4 + 1] = v.y;
    tbuf[yy][x4 + 2] = v.z; tbuf[yy][x4 + 3] = v.w;
  }
  __syncthreads();
  {
    const int yy = tid >> 3, x4 = (tid & 7) << 2;
    half4 h;
#pragma unroll
    for (int e = 0; e < 4; ++e) h[e] = (_Float16)tbuf[x4 + e][yy];
    *reinterpret_cast<half4*>(dst + (long)(c0 + yy) * R + r0 + x4) = h;
  }
}

// ---------------------------------------------------------------------------
// Per (b,i), fused: qr (in-block) + scores + rel-dot + mask + softmax.
// ---------------------------------------------------------------------------
__global__ __launch_bounds__(256)
void relsm3(const float* __restrict__ rel, const float* __restrict__ graph,
            const _Float16* __restrict__ q16, const float* __restrict__ Wr,
            const float* __restrict__ br,
            _Float16* __restrict__ sc)   // in: scores f16, out: probs f16
{
  __shared__ float s[12][512];           // phase 0/1 overlay: wr[64][65]+qrow
  __shared__ float qrl[12][64];
  __shared__ float gl[512];
  __shared__ float qb8[12];

  float* wrbuf = &s[0][0];               // [64][65] = 4160 floats
  float* qrowbuf = wrbuf + 64 * 65;      // [12][64] = 768 floats (<= 6144 tot)

  const int bi = blockIdx.x;
  const int b = bi >> 9, i = bi & 511;
  const int tid = threadIdx.x, lane = tid & 63, wid = tid >> 6;
  const int l15 = lane & 15, lk = (lane >> 4) * 8;

  // P0: stage Wr, q-row, graph
  for (int t = tid; t < 4096; t += 256) wrbuf[(t >> 6) * 65 + (t & 63)] = Wr[t];
  for (int t = tid; t < 768; t += 256) {
    const int h = t >> 6, d = t & 63;
    qrowbuf[h * 64 + d] = (float)q16[((long)((b * 12 + h) * 512 + i)) * 64 + d];
  }
  for (int t = tid; t < 512; t += 256) gl[t] = graph[(long)bi * 512 + t];
  __syncthreads();

  // P1: qr + qbr
  for (int o = tid; o < 768; o += 256) {
    const int h = o >> 6, r = o & 63;
    float ssum = 0.f;
#pragma unroll 8
    for (int d = 0; d < 64; ++d) ssum += qrowbuf[h * 64 + d] * wrbuf[r * 65 + d];
    qrl[h][r] = ssum;
  }
  if (tid < 12) {
    float ssum = 0.f;
#pragma unroll 8
    for (int d = 0; d < 64; ++d) ssum += qrowbuf[tid * 64 + d] * br[d];
    qb8[tid] = ssum * 0.125f;
  }
  __syncthreads();

  // P2: qa fragments + s init (overwrites wr/qrow overlay); vectorized half8
  half8 qa0 = {}, qa1 = {};
  if (l15 < 12) {
#pragma unroll
    for (int e = 0; e < 8; ++e) {
      qa0[e] = (_Float16)qrl[l15][lk + e];
      qa1[e] = (_Float16)qrl[l15][32 + lk + e];
    }
  }
#pragma unroll
  for (int t = 0; t < 3; ++t) {
    const int idx = t * 256 + tid;       // 768 half8-groups = 6144 elems
    const int h = idx >> 6, j8 = (idx & 63) << 3;
    const half8 v = *reinterpret_cast<const half8*>(
        &sc[(((long)(b * 12 + h) * 512) + i) * 512 + j8]);
    const float add = qb8[h];
#pragma unroll
    for (int e = 0; e < 8; ++e)
      s[h][j8 + e] = (float)v[e] + add + (1.0f - gl[j8 + e]) * (-1.0e9f);
  }
  __syncthreads();

  // P3: stream rel once, MFMA rel-dot, RMW s (no barriers inside)
  const long rbase = ((long)bi * 512 + wid * 16 + l15) * 64 + lk;
  const int jj0 = wid * 16 + l15;
  for (int jt = 0; jt < 512; jt += 64) {
    const float* rp = rel + rbase + (long)jt * 64;
    const float4 v0 = *reinterpret_cast<const float4*>(rp);
    const float4 v1 = *reinterpret_cast<const float4*>(rp + 4);
    const float4 v2 = *reinterpret_cast<const float4*>(rp + 32);
    const float4 v3 = *reinterpret_cast<const float4*>(rp + 36);
    half8 b0, b1;
    b0[0] = (_Float16)v0.x; b0[1] = (_Float16)v0.y; b0[2] = (_Float16)v0.z; b0[3] = (_Float16)v0.w;
    b0[4] = (_Float16)v1.x; b0[5] = (_Float16)v1.y; b0[6] = (_Float16)v1.z; b0[7] = (_Float16)v1.w;
    b1[0] = (_Float16)v2.x; b1[1] = (_Float16)v2.y; b1[2] = (_Float16)v2.z; b1[3] = (_Float16)v2.w;
    b1[4] = (_Float16)v3.x; b1[5] = (_Float16)v3.y; b1[6] = (_Float16)v3.z; b1[7] = (_Float16)v3.w;
    f32x4 acc = {};
    acc = __builtin_amdgcn_mfma_f32_16x16x32_f16(qa0, b0, acc, 0, 0, 0);
    acc = __builtin_amdgcn_mfma_f32_16x16x32_f16(qa1, b1, acc, 0, 0, 0);
#pragma unroll
    for (int r = 0; r < 4; ++r) {
      const int h = ((lane >> 4) << 2) + r;
      if (h < 12) s[h][jt + jj0] += acc[r] * 0.125f;
    }
  }
  __syncthreads();

  // P4: softmax + write probs as half2 (4B/lane stores)
  for (int h = wid; h < 12; h += 4) {
    float v0[4], v1[4];
    float mx = -3.4e38f;
#pragma unroll
    for (int t = 0; t < 4; ++t) {
      const int j0 = (t << 7) + (lane << 1);
      v0[t] = s[h][j0]; v1[t] = s[h][j0 + 1];
      mx = fmaxf(mx, fmaxf(v0[t], v1[t]));
    }
#pragma unroll
    for (int off = 32; off > 0; off >>= 1) mx = fmaxf(mx, __shfl_xor(mx, off, 64));
    float sum = 0.f;
#pragma unroll
    for (int t = 0; t < 4; ++t) {
      v0[t] = __expf(v0[t] - mx); v1[t] = __expf(v1[t] - mx);
      sum += v0[t] + v1[t];
    }
#pragma unroll
    for (int off = 32; off > 0; off >>= 1) sum += __shfl_xor(sum, off, 64);
    const float inv = 1.0f / sum;
    const long base = (((long)(b * 12 + h) * 512) + i) * 512;
#pragma unroll
    for (int t = 0; t < 4; ++t) {
      const int j0 = (t << 7) + (lane << 1);
      half2v pk = {(_Float16)(v0[t] * inv), (_Float16)(v1[t] * inv)};
      *reinterpret_cast<half2v*>(&sc[base + j0]) = pk;
    }
  }
}

// ---------------------------------------------------------------------------
// x = (f32)p0h + (f32)p1h + bias + res (fixed order), then LayerNorm over 768.
// Optional f16 secondary output.
// ---------------------------------------------------------------------------
__global__ __launch_bounds__(256)
void ln2h_kernel(const _Float16* __restrict__ p0, const _Float16* __restrict__ p1,
                 const float* __restrict__ bias, const float* __restrict__ res,
                 const float* __restrict__ g, const float* __restrict__ bta,
                 float* __restrict__ out, _Float16* __restrict__ out16)
{
  __shared__ float red[8];
  const long row = blockIdx.x;
  const int tid = threadIdx.x;
  const long o0i = row * 768 + tid, o1i = o0i + 256, o2i = o0i + 512;
  const float v0 = (float)p0[o0i] + (float)p1[o0i] + bias[tid] + res[o0i];
  const float v1 = (float)p0[o1i] + (float)p1[o1i] + bias[tid + 256] + res[o1i];
  const float v2 = (float)p0[o2i] + (float)p1[o2i] + bias[tid + 512] + res[o2i];
  float sum = v0 + v1 + v2;
#pragma unroll
  for (int off = 32; off > 0; off >>= 1) sum += __shfl_xor(sum, off, 64);
  const int wv = tid >> 6, ln = tid & 63;
  if (ln == 0) red[wv] = sum;
  __syncthreads();
  const float mean = (red[0] + red[1] + red[2] + red[3]) * (1.0f / 768.0f);
  const float d0 = v0 - mean, d1 = v1 - mean, d2 = v2 - mean;
  float sq = d0 * d0 + d1 * d1 + d2 * d2;
#pragma unroll
  for (int off = 32; off > 0; off >>= 1) sq += __shfl_xor(sq, off, 64);
  if (ln == 0) red[4 + wv] = sq;
  __syncthreads();
  const float var = (red[4] + red[5] + red[6] + red[7]) * (1.0f / 768.0f);
  const float rstd = rsqrtf(var + 1e-12f);
  const float o0 = g[tid] * d0 * rstd + bta[tid];
  const float o1 = g[tid + 256] * d1 * rstd + bta[tid + 256];
  const float o2 = g[tid + 512] * d2 * rstd + bta[tid + 512];
  float* orow = out + row * 768;
  orow[tid] = o0; orow[tid + 256] = o1; orow[tid + 512] = o2;
  if (out16) {
    _Float16* hrow = out16 + row * 768;
    hrow[tid] = (_Float16)o0; hrow[tid + 256] = (_Float16)o1; hrow[tid + 512] = (_Float16)o2;
  }
}

// ---------------------------------------------------------------------------
extern "C" void kernel_launch(void* const* d_in, const int* in_sizes, int n_in,
                              void* d_out, int out_size, void* d_ws, size_t ws_size,
                              hipStream_t stream)
{
  const float* hidden = (const float*)d_in[0];
  const float* graph  = (const float*)d_in[1];
  const float* rel    = (const float*)d_in[2];
  const float* Wq = (const float*)d_in[3];  const float* bq = (const float*)d_in[4];
  const float* Wk = (const float*)d_in[5];  const float* bk = (const float*)d_in[6];
  const float* Wv = (const float*)d_in[7];  const float* bv = (const float*)d_in[8];
  const float* Wr = (const float*)d_in[9];  const float* br = (const float*)d_in[10];
  const float* Wo = (const float*)d_in[11]; const float* bo = (const float*)d_in[12];
  const float* g1 = (const float*)d_in[13]; const float* b1 = (const float*)d_in[14];
  const float* Wi = (const float*)d_in[15]; const float* bi = (const float*)d_in[16];
  const float* Wf = (const float*)d_in[17]; const float* bff = (const float*)d_in[18];
  const float* g2 = (const float*)d_in[19]; const float* b2 = (const float*)d_in[20];
  float* out = (float*)d_out;

  // ---- workspace carving (bytes, 256B-aligned blocks)
  char* base = (char*)d_ws;
  size_t off = 0;
  auto carve = [&](size_t bytes) { void* p = base + off; off += (bytes + 255) & ~255UL; return p; };
  _Float16* h16   = (_Float16*)carve(2048L * 768 * 2);
  _Float16* w4t   = (_Float16*)carve(4L * 768 * 768 * 2);   // WqT,WkT,WvT,WoT
  _Float16* wiT   = (_Float16*)carve(3072L * 768 * 2);
  _Float16* wfT   = (_Float16*)carve(768L * 3072 * 2);
  _Float16* q16   = (_Float16*)carve(2048L * 768 * 2);      // (b,h,s,d)
  _Float16* k16   = (_Float16*)carve(2048L * 768 * 2);      // (b,h,s,d)
  _Float16* v16t  = (_Float16*)carve(2048L * 768 * 2);      // (b,h,d,s)
  _Float16* sc16  = (_Float16*)carve(48L * 512 * 512 * 2);  // scores -> probs
  _Float16* ctx16 = (_Float16*)carve(2048L * 768 * 2);      // (b,s,h,d)
  _Float16* pk16  = (_Float16*)carve(2L * 2048 * 768 * 2);  // split-K partials f16
  float*    attn  = (float*)carve(2048L * 768 * 4);
  _Float16* attn16= (_Float16*)carve(2048L * 768 * 2);
  _Float16* inter16=(_Float16*)carve(2048L * 3072 * 2);

  const dim3 blk(256);
  const long W44 = 768L * 768;
  const long PSTR = 2048L * 768;

  // ---- fused operand conversion (one launch)
  hipLaunchKernelGGL(prep_kernel, dim3(8448), blk, 0, stream,
    Wq, Wk, Wv, Wo, Wi, Wf, hidden, w4t, wiT, wfT, h16);

  // ---- QKV fused (z=0,1,2): 64x96 tiles, BK=64, grid 768
  hipLaunchKernelGGL((gemm16<2, 3, 2, 2, 0>), dim3(32, 8, 3), blk, 0, stream,
    h16, w4t, bq, bk, bv,
    (float*)nullptr, q16, k16, v16t,
    2048, 768, 768, 768, 768, 768, 0L, W44, 0L, 1.0f);

  // ---- scores = (q @ k^T)/8 f16: 128x128, K=64 single-phase, grid 768
  hipLaunchKernelGGL((gemm16<4, 4, 2, 1, 1>), dim3(4, 4, 48), blk, 0, stream,
    q16, k16, (const float*)nullptr, (const float*)nullptr, (const float*)nullptr,
    (float*)nullptr, sc16, (_Float16*)nullptr, (_Float16*)nullptr,
    512, 512, 64, 64, 64, 512, 32768L, 32768L, 262144L, 0.125f);

  // ---- qr (in-block) + rel term + mask + softmax (in-place f16)
  hipLaunchKernelGGL(relsm3, dim3(2048), blk, 0, stream,
    rel, graph, q16, Wr, br, sc16);

  // ---- ctx = probs @ v : 32x64 tiles, BK=128 (4 phases), grid 768, 3/CU
  hipLaunchKernelGGL((gemm16<1, 2, 4, 2, 2>), dim3(16, 1, 48), blk, 0, stream,
    sc16, v16t, (const float*)nullptr, (const float*)nullptr, (const float*)nullptr,
    (float*)nullptr, ctx16, (_Float16*)nullptr, (_Float16*)nullptr,
    512, 64, 512, 512, 512, 768, 262144L, 32768L, 0L, 1.0f);

  // ---- ctx @ Wo split-K (z=2 halves of 768), 64x96, BK=128 (3 phases), grid 512
  hipLaunchKernelGGL((gemm16<2, 3, 4, 2, 6>), dim3(32, 8, 2), blk, 0, stream,
    ctx16, w4t + 3 * W44, (const float*)nullptr, (const float*)nullptr, (const float*)nullptr,
    (float*)nullptr, pk16, (_Float16*)nullptr, (_Float16*)nullptr,
    2048, 768, 384, 768, 768, 768, 384L, 384L, PSTR, 1.0f);
  hipLaunchKernelGGL(ln2h_kernel, dim3(2048), blk, 0, stream,
    pk16, pk16 + PSTR, bo, hidden, g1, b1, attn, attn16);

  // ---- inter = gelu(attn @ Wi + bi) : 128x96, BK=64, grid 512
  hipLaunchKernelGGL((gemm16<4, 3, 2, 2, 4>), dim3(16, 32, 1), blk, 0, stream,
    attn16, wiT, bi, (const float*)nullptr, (const float*)nullptr,
    (float*)nullptr, inter16, (_Float16*)nullptr, (_Float16*)nullptr,
    2048, 3072, 768, 768, 768, 3072, 0L, 0L, 0L, 1.0f);

  // ---- inter @ Wf split-K (z=2 halves of 3072), 64x96, BK=128 (12 phases), grid 512
  hipLaunchKernelGGL((gemm16<2, 3, 4, 2, 6>), dim3(32, 8, 2), blk, 0, stream,
    inter16, wfT, (const float*)nullptr, (const float*)nullptr, (const float*)nullptr,
    (float*)nullptr, pk16, (_Float16*)nullptr, (_Float16*)nullptr,
    2048, 768, 1536, 3072, 3072, 768, 1536L, 1536L, PSTR, 1.0f);
  hipLaunchKernelGGL(ln2h_kernel, dim3(2048), blk, 0, stream,
    pk16, pk16 + PSTR, bff, attn, g2, b2, out, (_Float16*)nullptr);
}